// Round 1
// baseline (231.546 us; speedup 1.0000x reference)
//
#include <hip/hip_runtime.h>

// Problem constants (LinearCrossAttention)
#define BATCH 16
#define SEQ_N 4096
#define SEQ_M 1024
#define KDIM 512     // INPUT_DIM == COND_DIM == GEMM K
#define NHEADS 8
#define DHEAD 64
#define HIDDEN 512

typedef __attribute__((ext_vector_type(8))) short bf16x8;
typedef __attribute__((ext_vector_type(4))) float f32x4;
typedef unsigned short u16;
typedef unsigned int u32;

static __device__ __forceinline__ u16 f2bf(float f) {
  u32 u = __builtin_bit_cast(u32, f);
  u32 r = u + 0x7fffu + ((u >> 16) & 1u);   // round-to-nearest-even
  return (u16)(r >> 16);
}
static __device__ __forceinline__ float bf2f(u16 h) {
  u32 u = ((u32)h) << 16;
  return __builtin_bit_cast(float, u);
}
static __device__ __forceinline__ bf16x8 ld_frag(const u16* p) {
  // 8B-aligned only (pad-4 rows), so 2x b64 then assemble
  uint2 lo = *(const uint2*)p;
  uint2 hi = *(const uint2*)(p + 4);
  uint4 u = make_uint4(lo.x, lo.y, hi.x, hi.y);
  return __builtin_bit_cast(bf16x8, u);
}

// ---------------------------------------------------------------------------
// Shared GEMM: C[b] = A[b] @ B[b] (+bias).  A: [O, 512] row-major (f32 or
// bf16).  B: [512, ldn] f32 row-major (transposed+converted into LDS).
// Out: [O, ldn] f32 or bf16.  grid = (O/128, ldn/128, batch), 256 threads.
// ---------------------------------------------------------------------------
template<bool A_BF16, bool OUT_BF16, bool BIAS>
__global__ __launch_bounds__(256, 2) void gemm_k512(
    const void* __restrict__ Ap, long a_bstride,
    const float* __restrict__ Bp, long b_bstride,
    void* __restrict__ Op, long o_bstride,
    const float* __restrict__ bias, int ldn)
{
  constexpr int LDT = 68;                     // 64 + 4 pad (136B row stride)
  __shared__ u16 Ash[128 * LDT];              // [row][k]
  __shared__ u16 Bsh[128 * LDT];              // [n][k]  (B transposed)

  const int b = blockIdx.z;
  const long mtile = (long)blockIdx.x * 128;
  const long ntile = (long)blockIdx.y * 128;
  const int t = threadIdx.x;
  const int lane = t & 63;
  const int wv = t >> 6;
  const int wr = (wv >> 1) * 64, wc = (wv & 1) * 64;
  const int lrow = lane & 15, lkh = lane >> 4;

  const float* Bb = Bp + (long)b * b_bstride;

  f32x4 acc[4][4] = {};

  for (int kt = 0; kt < KDIM; kt += 64) {
    // ---- stage A tile [128][64] ----
    if constexpr (A_BF16) {
      const u16* Ab = (const u16*)Ap + (long)b * a_bstride;
      #pragma unroll
      for (int i = 0; i < 4; ++i) {
        int idx = t + i * 256;
        int row = idx >> 3, kc = idx & 7;
        uint4 v = *(const uint4*)(Ab + (mtile + row) * KDIM + kt + kc * 8);
        u16* d = &Ash[row * LDT + kc * 8];
        *(uint2*)d       = make_uint2(v.x, v.y);
        *(uint2*)(d + 4) = make_uint2(v.z, v.w);
      }
    } else {
      const float* Ab = (const float*)Ap + (long)b * a_bstride;
      #pragma unroll
      for (int i = 0; i < 4; ++i) {
        int idx = t + i * 256;
        int row = idx >> 3, kc = idx & 7;
        const float* src = Ab + (mtile + row) * KDIM + kt + kc * 8;
        float4 v0 = *(const float4*)src;
        float4 v1 = *(const float4*)(src + 4);
        u32 w0 = (u32)f2bf(v0.x) | ((u32)f2bf(v0.y) << 16);
        u32 w1 = (u32)f2bf(v0.z) | ((u32)f2bf(v0.w) << 16);
        u32 w2 = (u32)f2bf(v1.x) | ((u32)f2bf(v1.y) << 16);
        u32 w3 = (u32)f2bf(v1.z) | ((u32)f2bf(v1.w) << 16);
        u16* d = &Ash[row * LDT + kc * 8];
        *(uint2*)d       = make_uint2(w0, w1);
        *(uint2*)(d + 4) = make_uint2(w2, w3);
      }
    }
    // ---- stage B tile transposed: Bsh[n][k] from B[k][n] (f32 -> bf16) ----
    #pragma unroll
    for (int i = 0; i < 2; ++i) {
      int idx = t + i * 256;
      int nq = idx & 31;
      int kq = ((idx >> 5) ^ ((idx >> 2) & 7)) & 15;  // bijective; spreads LDS write banks
      float rr[4][4];
      #pragma unroll
      for (int kk = 0; kk < 4; ++kk) {
        float4 v = *(const float4*)(Bb + (long)(kt + kq * 4 + kk) * ldn + ntile + nq * 4);
        rr[kk][0] = v.x; rr[kk][1] = v.y; rr[kk][2] = v.z; rr[kk][3] = v.w;
      }
      #pragma unroll
      for (int jj = 0; jj < 4; ++jj) {
        u32 w0 = (u32)f2bf(rr[0][jj]) | ((u32)f2bf(rr[1][jj]) << 16);
        u32 w1 = (u32)f2bf(rr[2][jj]) | ((u32)f2bf(rr[3][jj]) << 16);
        *(uint2*)&Bsh[(nq * 4 + jj) * LDT + kq * 4] = make_uint2(w0, w1);
      }
    }
    __syncthreads();
    // ---- MFMA: each wave owns a 64x64 quadrant, 4x4 frags of 16x16x32 ----
    #pragma unroll
    for (int kk = 0; kk < 2; ++kk) {
      bf16x8 af[4], bfr[4];
      #pragma unroll
      for (int mi = 0; mi < 4; ++mi)
        af[mi] = ld_frag(&Ash[(wr + mi * 16 + lrow) * LDT + kk * 32 + lkh * 8]);
      #pragma unroll
      for (int ni = 0; ni < 4; ++ni)
        bfr[ni] = ld_frag(&Bsh[(wc + ni * 16 + lrow) * LDT + kk * 32 + lkh * 8]);
      #pragma unroll
      for (int mi = 0; mi < 4; ++mi)
        #pragma unroll
        for (int ni = 0; ni < 4; ++ni)
          acc[mi][ni] = __builtin_amdgcn_mfma_f32_16x16x32_bf16(af[mi], bfr[ni], acc[mi][ni], 0, 0, 0);
    }
    __syncthreads();
  }
  // ---- epilogue: D row = (lane>>4)*4 + r, col = lane&15 ----
  #pragma unroll
  for (int mi = 0; mi < 4; ++mi) {
    #pragma unroll
    for (int r = 0; r < 4; ++r) {
      long gr = mtile + wr + mi * 16 + lkh * 4 + r;
      float bv = 0.0f;
      if constexpr (BIAS) bv = bias[gr];
      #pragma unroll
      for (int ni = 0; ni < 4; ++ni) {
        long gc = ntile + wc + ni * 16 + lrow;
        float v = acc[mi][ni][r] + bv;
        if constexpr (OUT_BF16)
          ((u16*)Op)[(long)b * o_bstride + gr * ldn + gc] = f2bf(v);
        else
          ((float*)Op)[(long)b * o_bstride + gr * ldn + gc] = v;
      }
    }
  }
}

// ---------------------------------------------------------------------------
// K2: per (b,h): softmax over m of K rows, ctx[d][e] = sum_m Kexp[d][m]*V[e][m]
// via MFMA (V's natural [e][m] layout IS the B-operand [col][k] layout).
// grid = B*H blocks, 256 threads (4 waves split the m/K dimension).
// ---------------------------------------------------------------------------
__global__ __launch_bounds__(256, 2) void softmax_context(
    const u16* __restrict__ kv, float* __restrict__ ctx)
{
  constexpr int LDE = 132;                    // 128 + 4 pad
  __shared__ float rowmax[64], rowinv[64];
  __shared__ u16 Ke[64 * LDE];
  __shared__ u16 Vs[64 * LDE];
  __shared__ float pr[64 * 68];

  const int bh = blockIdx.x;
  const u16* Kr = kv + (long)(bh >> 3) * (1024 * 1024) + (long)(bh & 7) * (64 * 1024);
  const u16* Vr = Kr + 512 * 1024;

  const int t = threadIdx.x;
  const int lane = t & 63, wv = t >> 6;
  const int lrow = lane & 15, lkh = lane >> 4;
  const int d4 = t >> 2, q4 = t & 3;

  // phase A: row max + 1/sum(exp)
  {
    const u16* row = Kr + d4 * 1024 + q4 * 256;
    float mx = -3e38f;
    for (int i = 0; i < 256; i += 8) {
      uint4 v = *(const uint4*)(row + i);
      u32 ws[4] = {v.x, v.y, v.z, v.w};
      #pragma unroll
      for (int j = 0; j < 4; ++j) {
        mx = fmaxf(mx, __builtin_bit_cast(float, ws[j] << 16));
        mx = fmaxf(mx, __builtin_bit_cast(float, ws[j] & 0xffff0000u));
      }
    }
    mx = fmaxf(mx, __shfl_xor(mx, 1));
    mx = fmaxf(mx, __shfl_xor(mx, 2));
    float s = 0.f;
    for (int i = 0; i < 256; i += 8) {
      uint4 v = *(const uint4*)(row + i);
      u32 ws[4] = {v.x, v.y, v.z, v.w};
      #pragma unroll
      for (int j = 0; j < 4; ++j) {
        s += __expf(__builtin_bit_cast(float, ws[j] << 16) - mx);
        s += __expf(__builtin_bit_cast(float, ws[j] & 0xffff0000u) - mx);
      }
    }
    s += __shfl_xor(s, 1);
    s += __shfl_xor(s, 2);
    if (q4 == 0) { rowmax[d4] = mx; rowinv[d4] = 1.f / s; }
  }
  __syncthreads();

  f32x4 cacc[4][4] = {};

  for (int mc = 0; mc < 8; ++mc) {
    // stage Ke (normalized exp, bf16) and Vs (copy) for 128-m chunk
    {
      int d = t >> 2, j = t & 3;
      int m0 = mc * 128 + j * 32;
      float mx = rowmax[d], inv = rowinv[d];
      const u16* src = Kr + d * 1024 + m0;
      u16* dst = &Ke[d * LDE + j * 32];
      #pragma unroll
      for (int cq = 0; cq < 4; ++cq) {
        uint4 v = *(const uint4*)(src + cq * 8);
        u32 in[4] = {v.x, v.y, v.z, v.w};
        u32 out[4];
        #pragma unroll
        for (int j2 = 0; j2 < 4; ++j2) {
          float lo = __builtin_bit_cast(float, in[j2] << 16);
          float hi = __builtin_bit_cast(float, in[j2] & 0xffff0000u);
          out[j2] = (u32)f2bf(__expf(lo - mx) * inv) |
                    ((u32)f2bf(__expf(hi - mx) * inv) << 16);
        }
        *(uint2*)(dst + cq * 8)     = make_uint2(out[0], out[1]);
        *(uint2*)(dst + cq * 8 + 4) = make_uint2(out[2], out[3]);
      }
      const u16* vsrc = Vr + d * 1024 + m0;
      u16* vdst = &Vs[d * LDE + j * 32];
      #pragma unroll
      for (int cq = 0; cq < 4; ++cq) {
        uint4 v = *(const uint4*)(vsrc + cq * 8);
        *(uint2*)(vdst + cq * 8)     = make_uint2(v.x, v.y);
        *(uint2*)(vdst + cq * 8 + 4) = make_uint2(v.z, v.w);
      }
    }
    __syncthreads();
    // wave wv takes k-slice wv*32 of this 128-chunk
    bf16x8 ka[4], vb[4];
    #pragma unroll
    for (int mi = 0; mi < 4; ++mi)
      ka[mi] = ld_frag(&Ke[(mi * 16 + lrow) * LDE + wv * 32 + lkh * 8]);
    #pragma unroll
    for (int ni = 0; ni < 4; ++ni)
      vb[ni] = ld_frag(&Vs[(ni * 16 + lrow) * LDE + wv * 32 + lkh * 8]);
    #pragma unroll
    for (int mi = 0; mi < 4; ++mi)
      #pragma unroll
      for (int ni = 0; ni < 4; ++ni)
        cacc[mi][ni] = __builtin_amdgcn_mfma_f32_16x16x32_bf16(ka[mi], vb[ni], cacc[mi][ni], 0, 0, 0);
    __syncthreads();
  }

  // cross-wave reduce (serialized adds into pr)
  for (int w = 0; w < 4; ++w) {
    if (wv == w) {
      #pragma unroll
      for (int mi = 0; mi < 4; ++mi)
        #pragma unroll
        for (int ni = 0; ni < 4; ++ni)
          #pragma unroll
          for (int r = 0; r < 4; ++r) {
            float* p = &pr[(mi * 16 + lkh * 4 + r) * 68 + (ni * 16 + lrow)];
            float v = cacc[mi][ni][r];
            if (w == 0) *p = v; else *p += v;
          }
    }
    __syncthreads();
  }
  float* cg = ctx + (long)bh * 4096;
  for (int i = 0; i < 16; ++i) {
    int o = t + i * 256;
    cg[o] = 0.125f * pr[(o >> 6) * 68 + (o & 63)];  // fold q-scale (DIM_HEAD^-0.5)
  }
}

// ---------------------------------------------------------------------------
// K3a: U[b][o][h*64+d] = scale-folded sum_e Wo[o][h*64+e] * ctx[b,h,d,e]
// grid = (B*H, 4 d-quarters), 256 threads.
// ---------------------------------------------------------------------------
__global__ __launch_bounds__(256) void compose_u(
    const float* __restrict__ ctx, const float* __restrict__ Wo, u16* __restrict__ U)
{
  __shared__ float cs[16 * 64];
  const int bh = blockIdx.x, dq = blockIdx.y;
  const int b = bh >> 3, h = bh & 7;
  const int t = threadIdx.x;
  const float* cgrp = ctx + (long)bh * 4096 + dq * 16 * 64;
  for (int i = t; i < 1024; i += 256) cs[i] = cgrp[i];
  __syncthreads();
  #pragma unroll
  for (int rep = 0; rep < 2; ++rep) {
    int o = rep * 256 + t;
    const float* wrow = Wo + (long)o * HIDDEN + h * 64;
    float acc[16] = {};
    for (int e = 0; e < 64; ++e) {
      float w = wrow[e];
      #pragma unroll
      for (int dd = 0; dd < 16; ++dd) acc[dd] += w * cs[dd * 64 + e];
    }
    u16* urow = U + (long)b * (512 * 512) + (long)o * 512 + h * 64 + dq * 16;
    #pragma unroll
    for (int dd = 0; dd < 16; ++dd) urow[dd] = f2bf(acc[dd]);
  }
}

// ---------------------------------------------------------------------------
extern "C" void kernel_launch(void* const* d_in, const int* in_sizes, int n_in,
                              void* d_out, int out_size, void* d_ws, size_t ws_size,
                              hipStream_t stream)
{
  const float* x   = (const float*)d_in[0];  // [16, 512, 4096]
  const float* c   = (const float*)d_in[1];  // [16, 512, 1024]
  const float* Wq  = (const float*)d_in[2];  // [512, 512]
  const float* Wkv = (const float*)d_in[3];  // [1024, 512]
  const float* Wo  = (const float*)d_in[4];  // [512, 512]
  const float* bo  = (const float*)d_in[5];  // [512]

  // workspace layout (52.4 MB total)
  char* ws = (char*)d_ws;
  u16*   kv   = (u16*)ws;                      // 16*1024*1024 bf16 = 33.5 MB
  float* ctx  = (float*)(ws + 33554432);       // 16*8*64*64 f32    =  2.1 MB
  u16*   U    = (u16*)(ws + 35651584);         // 16*512*512 bf16   =  8.4 MB
  u16*   Weff = (u16*)(ws + 44040192);         // 16*512*512 bf16   =  8.4 MB

  // K1: kv[b] = Wkv @ c[b]            (A f32 shared, out bf16)
  gemm_k512<false, true, false><<<dim3(8, 8, 16), 256, 0, stream>>>(
      Wkv, 0, c, 512L * 1024, kv, 1024L * 1024, nullptr, 1024);
  // K2: softmax + context
  softmax_context<<<dim3(128), 256, 0, stream>>>(kv, ctx);
  // K3a: U = scale * Wo_h @ ctx_h^T
  compose_u<<<dim3(128, 4), 256, 0, stream>>>(ctx, Wo, U);
  // K3b: Weff[b] = U[b] @ Wq          (A bf16 per batch, B shared, out bf16)
  gemm_k512<true, true, false><<<dim3(4, 4, 16), 256, 0, stream>>>(
      U, 512L * 512, Wq, 0, Weff, 512L * 512, nullptr, 512);
  // K4: Y[b] = Weff[b] @ x[b] + bo    (out f32 + bias)
  gemm_k512<true, false, true><<<dim3(4, 32, 16), 256, 0, stream>>>(
      Weff, 512L * 512, x, 512L * 4096, d_out, 512L * 4096, bo, 4096);
}